// Round 9
// baseline (822.914 us; speedup 1.0000x reference)
//
#include <hip/hip_runtime.h>
#include <math.h>

#define NBOND 7
#define NLAY 8
#define NTYPE 6
#define NNODES 16384   // B*N = 128*128
#define PX 136         // LDS pitch in halves (272 B, 16B-aligned; 68 dw % 32 = 4 -> conflict-clean)
#define NDESC 264      // 8 XCDs x 33 desc slots (>= 262 max active 64-node slices)

typedef _Float16 half8 __attribute__((ext_vector_type(8)));
typedef _Float16 half4 __attribute__((ext_vector_type(4)));
typedef float floatx16 __attribute__((ext_vector_type(16)));

__device__ __forceinline__ float sig_(float x) { return 1.0f / (1.0f + __expf(-x)); }
// D-layout for 32x32 MFMA: col = lane&31, row = (reg&3) + 8*(reg>>2) + 4*(lane>>5)
__device__ __forceinline__ int drow_(int reg, int hi) { return (reg & 3) + 8 * (reg >> 2) + 4 * hi; }

__device__ __forceinline__ _Float16 hi_(float v) { return (_Float16)v; }
__device__ __forceinline__ _Float16 lo_(float v) { return (_Float16)(v - (float)(_Float16)v); }

// ---------------------------------------------------------------- setup
__global__ void setup_kernel(const float* __restrict__ h, float* __restrict__ hT,
                             int* __restrict__ counts, int* __restrict__ bucket)
{
    int gid = blockIdx.x * 256 + threadIdx.x;
    int node = gid >> 7, d = gid & 127;
    hT[gid] = (d < 75) ? h[node * 75 + d] : 0.0f;
    if (gid < NNODES) {
        float a = h[gid * 75];
        int tt = 5;
        if      (a == 6.0f) tt = 0;
        else if (a == 7.0f) tt = 1;
        else if (a == 8.0f) tt = 2;
        else if (a == 9.0f) tt = 3;
        else if (a == 0.0f) tt = 4;
        int slot = atomicAdd(&counts[tt], 1);
        bucket[tt * NNODES + slot] = gid;
    }
}

// Dense GRU block descriptors over 64-node slices: desc[i] = tt | (slice<<3).
__global__ void build_desc_kernel(const int* __restrict__ counts, int* __restrict__ desc)
{
    if (threadIdx.x != 0 || blockIdx.x != 0) return;
    int i = 0;
    for (int tt = 0; tt < NTYPE; ++tt) {
        int nb = (counts[tt] + 63) >> 6;
        for (int s = 0; s < nb; ++s) desc[i++] = tt | (s << 3);
    }
    while (i < NDESC) desc[i++] = -1;
}

// ---------------------------------------------------------------- weight packing (fp32 -> split fp16 hi/lo planes)
// msgW: [(kb*8+l)][c 0..15][plane hi/lo][e 0..127][j 0..7]  (j along input dim d)
__global__ void pack_msg_kernel(const float* __restrict__ msgW, _Float16* __restrict__ Wp)
{
    int idx = blockIdx.x * 256 + threadIdx.x;
    if (idx >= NBOND * NLAY * 16 * 128) return;
    int e  = idx & 127;
    int c  = (idx >> 7) & 15;
    int kl = idx >> 11;
    const float* src = msgW + ((size_t)kl * 128 + e) * 128 + c * 8;
    float4 u = *(const float4*)src;
    float4 v = *(const float4*)(src + 4);
    float av[8] = {u.x, u.y, u.z, u.w, v.x, v.y, v.z, v.w};
    half8 hh, ll;
    #pragma unroll
    for (int j = 0; j < 8; ++j) { hh[j] = hi_(av[j]); ll[j] = lo_(av[j]); }
    _Float16* dst = Wp + ((size_t)kl * 16 + c) * 2048;
    *(half8*)(dst + e * 8)        = hh;
    *(half8*)(dst + 1024 + e * 8) = ll;
}

// GRU: [(vt*2+mat)][c 0..15][plane hi/lo][col 0..383][j 0..7]
__global__ void pack_gru_kernel(const float* __restrict__ Wih, const float* __restrict__ Whh,
                                _Float16* __restrict__ Wp)
{
    int idx = blockIdx.x * 256 + threadIdx.x;
    if (idx >= 2 * NTYPE * 2 * 16 * 384) return;
    int col = idx % 384;
    int c   = (idx / 384) & 15;
    int vm  = idx / 6144;       // (vt*2 + mat), vt = v*6+tt
    int mat = vm & 1;
    int vt  = vm >> 1;
    const float* src = (mat ? Whh : Wih) + ((size_t)vt * 384 + col) * 128 + c * 8;
    float4 u = *(const float4*)src;
    float4 v = *(const float4*)(src + 4);
    float av[8] = {u.x, u.y, u.z, u.w, v.x, v.y, v.z, v.w};
    half8 hh, ll;
    #pragma unroll
    for (int j = 0; j < 8; ++j) { hh[j] = hi_(av[j]); ll[j] = lo_(av[j]); }
    _Float16* dst = Wp + (size_t)vm * 98304 + (size_t)c * 6144;
    *(half8*)(dst + col * 8)        = hh;
    *(half8*)(dst + 3072 + col * 8) = ll;
}

// ---------------------------------------------------------------- MLP + aggregation (split-fp16 MFMA)
// r4 structure (best measured: 150.5 us). 1D grid with XCD-chunked bid->(kb,b):
// XCD k (bid%8==k) owns work ids k*112..k*112+111 -> each XCD touches <=2 of
// the 7 bond-type weight sets (<=1 MB, fits its L2) instead of all 3.67 MB.
__global__ __launch_bounds__(512, 4) void mlp_agg_mfma(
    const float* __restrict__ hin, const _Float16* __restrict__ Wp,
    const float* __restrict__ gmat, float* __restrict__ m_non, float* __restrict__ m_uni)
{
    __shared__ _Float16 Xhi[128 * PX];
    __shared__ _Float16 Xlo[128 * PX];

    const int bid = blockIdx.x;
    const int w12 = (bid & 7) * 112 + (bid >> 3);   // bijective over 0..895
    const int kb = w12 >> 7, b = w12 & 127;
    const int t = threadIdx.x;
    const int wave = t >> 6, lane = t & 63, lo = lane & 31, hi = lane >> 5;
    const int ctw = wave & 3, rh = wave >> 2;   // MLP: col-tile, row-half
    const int wcol = ctw * 32 + lo;             // MLP-phase output column

    // stage layer-0 activations (fp32 -> hi/lo fp16)
    for (int q = t; q < 128 * 32; q += 512) {
        int r = q >> 5, c4 = q & 31;
        float4 v = *(const float4*)(hin + ((size_t)(b * 128 + r)) * 128 + c4 * 4);
        half4 hh, ll;
        hh[0] = hi_(v.x); ll[0] = lo_(v.x);
        hh[1] = hi_(v.y); ll[1] = lo_(v.y);
        hh[2] = hi_(v.z); ll[2] = lo_(v.z);
        hh[3] = hi_(v.w); ll[3] = lo_(v.w);
        *(half4*)(Xhi + r * PX + c4 * 4) = hh;
        *(half4*)(Xlo + r * PX + c4 * 4) = ll;
    }
    __syncthreads();

    floatx16 acc[2];

    #pragma unroll 1
    for (int l = 0; l < NLAY; ++l) {
        #pragma unroll
        for (int r2 = 0; r2 < 2; ++r2) acc[r2] = (floatx16)0.0f;
        const _Float16* wb = Wp + ((size_t)(kb * NLAY + l) * 16) * 2048;

        #pragma unroll
        for (int kk = 0; kk < 8; ++kk) {
            const _Float16* bp = wb + (size_t)(kk * 2 + hi) * 2048;
            half8 b_h = *(const half8*)(bp + wcol * 8);
            half8 b_l = *(const half8*)(bp + 1024 + wcol * 8);
            #pragma unroll
            for (int r2 = 0; r2 < 2; ++r2) {
                int rrow = (rh * 2 + r2) * 32 + lo;
                half8 a_h = *(const half8*)(Xhi + rrow * PX + kk * 16 + hi * 8);
                half8 a_l = *(const half8*)(Xlo + rrow * PX + kk * 16 + hi * 8);
                acc[r2] = __builtin_amdgcn_mfma_f32_32x32x16_f16(a_h, b_h, acc[r2], 0, 0, 0);
                acc[r2] = __builtin_amdgcn_mfma_f32_32x32x16_f16(a_h, b_l, acc[r2], 0, 0, 0);
                acc[r2] = __builtin_amdgcn_mfma_f32_32x32x16_f16(a_l, b_h, acc[r2], 0, 0, 0);
            }
        }
        __syncthreads();   // all waves' X reads for layer l done

        if (l < NLAY - 1) {
            // writeback: fixed column wcol, rows (rh*2+r2)*32+drow
            #pragma unroll
            for (int r2 = 0; r2 < 2; ++r2)
                #pragma unroll
                for (int reg = 0; reg < 16; ++reg) {
                    int n = (rh * 2 + r2) * 32 + drow_(reg, hi);
                    float vv = fmaxf(acc[r2][reg], 0.0f);
                    Xhi[n * PX + wcol] = hi_(vv);
                    Xlo[n * PX + wcol] = lo_(vv);
                }
        } else {
            // final layer: Xt[e][m]; lane's fixed dim IS e=wcol -> contiguous half4 in m
            #pragma unroll
            for (int r2 = 0; r2 < 2; ++r2)
                #pragma unroll
                for (int s = 0; s < 4; ++s) {
                    int m0 = (rh * 2 + r2) * 32 + 8 * s + 4 * hi;
                    half4 hh, ll;
                    #pragma unroll
                    for (int j = 0; j < 4; ++j) {
                        float vv = acc[r2][4 * s + j];
                        hh[j] = hi_(vv); ll[j] = lo_(vv);
                    }
                    *(half4*)(Xhi + wcol * PX + m0) = hh;
                    *(half4*)(Xlo + wcol * PX + m0) = ll;
                }
        }
        __syncthreads();
    }

    // ---- aggregation: m[n][d] = sum_m g[b,kb,n,m]*xb[m][d]; A = g (inline split), B = Xt ----
    const int rtw = wave & 3, ch = wave >> 2;
    const int row = rtw * 32 + lo;
    #pragma unroll
    for (int c2 = 0; c2 < 2; ++c2) acc[c2] = (floatx16)0.0f;
    const float* grow = gmat + (size_t)(b * NBOND + kb) * 16384;

    #pragma unroll 2
    for (int kk = 0; kk < 8; ++kk) {
        const float* gp = grow + (size_t)row * 128 + kk * 16 + hi * 8;
        float4 u = *(const float4*)gp, v2 = *(const float4*)(gp + 4);
        float av[8] = {u.x, u.y, u.z, u.w, v2.x, v2.y, v2.z, v2.w};
        half8 a_h, a_l;
        #pragma unroll
        for (int j = 0; j < 8; ++j) { a_h[j] = hi_(av[j]); a_l[j] = lo_(av[j]); }
        #pragma unroll
        for (int c2 = 0; c2 < 2; ++c2) {
            int ct = ch * 2 + c2;
            half8 b_h = *(const half8*)(Xhi + (ct * 32 + lo) * PX + kk * 16 + hi * 8);
            half8 b_l = *(const half8*)(Xlo + (ct * 32 + lo) * PX + kk * 16 + hi * 8);
            acc[c2] = __builtin_amdgcn_mfma_f32_32x32x16_f16(a_h, b_h, acc[c2], 0, 0, 0);
            acc[c2] = __builtin_amdgcn_mfma_f32_32x32x16_f16(a_h, b_l, acc[c2], 0, 0, 0);
            acc[c2] = __builtin_amdgcn_mfma_f32_32x32x16_f16(a_l, b_h, acc[c2], 0, 0, 0);
        }
    }

    if (kb == NBOND - 1) {
        #pragma unroll
        for (int c2 = 0; c2 < 2; ++c2)
            #pragma unroll
            for (int reg = 0; reg < 16; ++reg) {
                int n = rtw * 32 + drow_(reg, hi);
                m_uni[((size_t)(b * 128 + n)) * 128 + (ch * 2 + c2) * 32 + lo] = acc[c2][reg];
            }
    } else {
        #pragma unroll
        for (int c2 = 0; c2 < 2; ++c2)
            #pragma unroll
            for (int reg = 0; reg < 16; ++reg) {
                int n = rtw * 32 + drow_(reg, hi);
                atomicAdd(m_non + ((size_t)(b * 128 + n)) * 128 + (ch * 2 + c2) * 32 + lo,
                          acc[c2][reg]);
            }
    }
}

// ---------------------------------------------------------------- grouped GRU (split-fp16 MFMA)
// 64-node blocks: each kk's 12 weight fragments are reused IN REGISTERS by two
// 32-row groups -> 36 MFMAs per 12 loads (2x the reuse of the 32-node version),
// total weight traffic per dispatch halves (400 -> 200 MB). Accumulators
// 2x4x16 = 128 VGPRs -> launch_bounds(256,2) for the 256-VGPR budget.
// LDS 69.6 KB; ~258 blocks (~1/CU). Block owns its 64 nodes exclusively ->
// in-place hT update: v=0 stores, v=1 read-add-stores. No atomics.
__global__ __launch_bounds__(256, 2) void gru_mfma(
    float* __restrict__ hT,
    const float* __restrict__ m_non, const float* __restrict__ m_uni,
    const int* __restrict__ counts, const int* __restrict__ bucket,
    const int* __restrict__ desc,
    const _Float16* __restrict__ Wp, const float* __restrict__ bihp, const float* __restrict__ bhhp)
{
    __shared__ _Float16 Xh[64 * PX], Xl[64 * PX], Mh[64 * PX], Ml[64 * PX];
    __shared__ int bl[64];

    const int bid = blockIdx.x;
    const int dv = desc[(bid & 7) * (NDESC / 8) + (bid >> 3)];
    if (dv < 0) return;
    const int tt = dv & 7;
    const int base = (dv >> 3) * 64;
    const int t = threadIdx.x;
    const int cnt = counts[tt];
    const int nn = min(64, cnt - base);
    if (t < 64) bl[t] = (t < nn) ? bucket[tt * NNODES + base + t] : -1;
    __syncthreads();

    // stage X once (64 gathered h rows, split fp16, zero-fill inactive)
    for (int q = t; q < 64 * 32; q += 256) {
        int r = q >> 5, c4 = q & 31;
        float4 xv = make_float4(0.f, 0.f, 0.f, 0.f);
        int node = bl[r];
        if (node >= 0) xv = *(const float4*)(hT + (size_t)node * 128 + c4 * 4);
        half4 hh, ll;
        hh[0] = hi_(xv.x); ll[0] = lo_(xv.x);
        hh[1] = hi_(xv.y); ll[1] = lo_(xv.y);
        hh[2] = hi_(xv.z); ll[2] = lo_(xv.z);
        hh[3] = hi_(xv.w); ll[3] = lo_(xv.w);
        *(half4*)(Xh + r * PX + c4 * 4) = hh;
        *(half4*)(Xl + r * PX + c4 * 4) = ll;
    }

    const int wave = t >> 6, lane = t & 63, lo = lane & 31, hi = lane >> 5;
    const int d = wave * 32 + lo;

    #pragma unroll 1
    for (int v = 0; v < 2; ++v) {
        const float* msrc = v ? m_uni : m_non;
        __syncthreads();   // v=0: X-stage commit; v=1: prior M readers done
        for (int q = t; q < 64 * 32; q += 256) {
            int r = q >> 5, c4 = q & 31;
            float4 mv = make_float4(0.f, 0.f, 0.f, 0.f);
            int node = bl[r];
            if (node >= 0) mv = *(const float4*)(msrc + (size_t)node * 128 + c4 * 4);
            half4 hh, ll;
            hh[0] = hi_(mv.x); ll[0] = lo_(mv.x);
            hh[1] = hi_(mv.y); ll[1] = lo_(mv.y);
            hh[2] = hi_(mv.z); ll[2] = lo_(mv.z);
            hh[3] = hi_(mv.w); ll[3] = lo_(mv.w);
            *(half4*)(Mh + r * PX + c4 * 4) = hh;
            *(half4*)(Ml + r * PX + c4 * 4) = ll;
        }
        __syncthreads();

        const int vt = v * NTYPE + tt;
        const _Float16* pih = Wp + (size_t)(vt * 2 + 0) * 98304;
        const _Float16* phh = Wp + (size_t)(vt * 2 + 1) * 98304;

        floatx16 ar[2], az[2], ax[2], ah[2];
        #pragma unroll
        for (int r2 = 0; r2 < 2; ++r2) {
            ar[r2] = (floatx16)0.0f; az[r2] = (floatx16)0.0f;
            ax[r2] = (floatx16)0.0f; ah[r2] = (floatx16)0.0f;
        }

        #pragma unroll 2
        for (int kk = 0; kk < 8; ++kk) {
            int koff = kk * 16 + hi * 8;
            half8 xh[2], xl[2], mh[2], ml[2];
            #pragma unroll
            for (int r2 = 0; r2 < 2; ++r2) {
                int rr = r2 * 32 + lo;
                xh[r2] = *(const half8*)(Xh + rr * PX + koff);
                xl[r2] = *(const half8*)(Xl + rr * PX + koff);
                mh[r2] = *(const half8*)(Mh + rr * PX + koff);
                ml[r2] = *(const half8*)(Ml + rr * PX + koff);
            }
            const _Float16* ci = pih + (size_t)(kk * 2 + hi) * 6144;
            const _Float16* ch = phh + (size_t)(kk * 2 + hi) * 6144;

            // r gate, input side
            {
                half8 wh = *(const half8*)(ci + (0 + d) * 8);
                half8 wl = *(const half8*)(ci + 3072 + (0 + d) * 8);
                #pragma unroll
                for (int r2 = 0; r2 < 2; ++r2) {
                    ar[r2] = __builtin_amdgcn_mfma_f32_32x32x16_f16(xh[r2], wh, ar[r2], 0, 0, 0);
                    ar[r2] = __builtin_amdgcn_mfma_f32_32x32x16_f16(xh[r2], wl, ar[r2], 0, 0, 0);
                    ar[r2] = __builtin_amdgcn_mfma_f32_32x32x16_f16(xl[r2], wh, ar[r2], 0, 0, 0);
                }
            }
            // r gate, hidden side
            {
                half8 wh = *(const half8*)(ch + (0 + d) * 8);
                half8 wl = *(const half8*)(ch + 3072 + (0 + d) * 8);
                #pragma unroll
                for (int r2 = 0; r2 < 2; ++r2) {
                    ar[r2] = __builtin_amdgcn_mfma_f32_32x32x16_f16(mh[r2], wh, ar[r2], 0, 0, 0);
                    ar[r2] = __builtin_amdgcn_mfma_f32_32x32x16_f16(mh[r2], wl, ar[r2], 0, 0, 0);
                    ar[r2] = __builtin_amdgcn_mfma_f32_32x32x16_f16(ml[r2], wh, ar[r2], 0, 0, 0);
                }
            }
            // z gate, input side
            {
                half8 wh = *(const half8*)(ci + (128 + d) * 8);
                half8 wl = *(const half8*)(ci + 3072 + (128 + d) * 8);
                #pragma unroll
                for (int r2 = 0; r2 < 2; ++r2) {
                    az[r2] = __builtin_amdgcn_mfma_f32_32x32x16_f16(xh[r2], wh, az[r2], 0, 0, 0);
                    az[r2] = __builtin_amdgcn_mfma_f32_32x32x16_f16(xh[r2], wl, az[r2], 0, 0, 0);
                    az[r2] = __builtin_amdgcn_mfma_f32_32x32x16_f16(xl[r2], wh, az[r2], 0, 0, 0);
                }
            }
            // z gate, hidden side
            {
                half8 wh = *(const half8*)(ch + (128 + d) * 8);
                half8 wl = *(const half8*)(ch + 3072 + (128 + d) * 8);
                #pragma unroll
                for (int r2 = 0; r2 < 2; ++r2) {
                    az[r2] = __builtin_amdgcn_mfma_f32_32x32x16_f16(mh[r2], wh, az[r2], 0, 0, 0);
                    az[r2] = __builtin_amdgcn_mfma_f32_32x32x16_f16(mh[r2], wl, az[r2], 0, 0, 0);
                    az[r2] = __builtin_amdgcn_mfma_f32_32x32x16_f16(ml[r2], wh, az[r2], 0, 0, 0);
                }
            }
            // n gate, input side (ax)
            {
                half8 wh = *(const half8*)(ci + (256 + d) * 8);
                half8 wl = *(const half8*)(ci + 3072 + (256 + d) * 8);
                #pragma unroll
                for (int r2 = 0; r2 < 2; ++r2) {
                    ax[r2] = __builtin_amdgcn_mfma_f32_32x32x16_f16(xh[r2], wh, ax[r2], 0, 0, 0);
                    ax[r2] = __builtin_amdgcn_mfma_f32_32x32x16_f16(xh[r2], wl, ax[r2], 0, 0, 0);
                    ax[r2] = __builtin_amdgcn_mfma_f32_32x32x16_f16(xl[r2], wh, ax[r2], 0, 0, 0);
                }
            }
            // n gate, hidden side (ah)
            {
                half8 wh = *(const half8*)(ch + (256 + d) * 8);
                half8 wl = *(const half8*)(ch + 3072 + (256 + d) * 8);
                #pragma unroll
                for (int r2 = 0; r2 < 2; ++r2) {
                    ah[r2] = __builtin_amdgcn_mfma_f32_32x32x16_f16(mh[r2], wh, ah[r2], 0, 0, 0);
                    ah[r2] = __builtin_amdgcn_mfma_f32_32x32x16_f16(mh[r2], wl, ah[r2], 0, 0, 0);
                    ah[r2] = __builtin_amdgcn_mfma_f32_32x32x16_f16(ml[r2], wh, ah[r2], 0, 0, 0);
                }
            }
        }

        const float* bi = bihp + (size_t)vt * 384;
        const float* bh = bhhp + (size_t)vt * 384;
        float b_r  = bi[d] + bh[d];
        float b_z  = bi[128 + d] + bh[128 + d];
        float b_in = bi[256 + d];
        float b_hn = bh[256 + d];
        #pragma unroll
        for (int r2 = 0; r2 < 2; ++r2)
            #pragma unroll
            for (int reg = 0; reg < 16; ++reg) {
                int n = r2 * 32 + drow_(reg, hi);
                int node = bl[n];
                if (node < 0) continue;
                float r  = sig_(ar[r2][reg] + b_r);
                float z  = sig_(az[r2][reg] + b_z);
                float nv = tanhf(ax[r2][reg] + b_in + r * (ah[r2][reg] + b_hn));
                float mv = msrc[(size_t)node * 128 + d];   // fp32 m for z*m
                float val = (1.0f - z) * nv + z * mv;
                if (v == 0) hT[(size_t)node * 128 + d] = val;   // overwrite old h
                else        hT[(size_t)node * 128 + d] += val;  // block owns node
            }
    }
}

// ---------------------------------------------------------------- launch
extern "C" void kernel_launch(void* const* d_in, const int* in_sizes, int n_in,
                              void* d_out, int out_size, void* d_ws, size_t ws_size,
                              hipStream_t stream) {
    const float* g    = (const float*)d_in[0];
    const float* h    = (const float*)d_in[1];
    const float* msgW = (const float*)d_in[2];
    const float* Wih  = (const float*)d_in[3];
    const float* Whh  = (const float*)d_in[4];
    const float* bih  = (const float*)d_in[5];
    const float* bhh  = (const float*)d_in[6];
    float* hT = (float*)d_out;

    char* ws = (char*)d_ws;
    float* m_non = (float*)ws;                                   // 8 MB
    float* m_uni = m_non + (size_t)NNODES * 128;                 // 8 MB
    int* counts  = (int*)(ws + 2 * (size_t)NNODES * 128 * 4);
    int* bucket  = counts + 8;                                   // [6][16384]
    int* desc    = bucket + NTYPE * NNODES;                      // [264]
    _Float16* WpM = (_Float16*)(desc + NDESC);                   // 1,835,008 halves (3.67 MB)
    _Float16* WpG = WpM + (size_t)NBOND * NLAY * 16 * 2048;      // 2,359,296 halves (4.72 MB)

    (void)hipMemsetAsync(counts, 0, 8 * sizeof(int), stream);
    setup_kernel<<<NNODES * 128 / 256, 256, 0, stream>>>(h, hT, counts, bucket);
    build_desc_kernel<<<1, 64, 0, stream>>>(counts, desc);
    pack_msg_kernel<<<(NBOND * NLAY * 16 * 128 + 255) / 256, 256, 0, stream>>>(msgW, WpM);
    pack_gru_kernel<<<(2 * NTYPE * 2 * 16 * 384 + 255) / 256, 256, 0, stream>>>(Wih, Whh, WpG);

    for (int pass = 0; pass < 3; ++pass) {
        (void)hipMemsetAsync(m_non, 0, (size_t)NNODES * 128 * 4, stream);
        mlp_agg_mfma<<<dim3(NBOND * 128), 512, 0, stream>>>(hT, WpM, g, m_non, m_uni);
        gru_mfma<<<dim3(NDESC), 256, 0, stream>>>(hT, m_non, m_uni, counts, bucket, desc,
                                                  WpG, bih, bhh);
    }
}